// Round 8
// baseline (162.934 us; speedup 1.0000x reference)
//
#include <hip/hip_runtime.h>

typedef _Float16 f16;
typedef f16 f16x8 __attribute__((ext_vector_type(8)));
typedef f16 f16x4 __attribute__((ext_vector_type(4)));
typedef float f32x4 __attribute__((ext_vector_type(4)));
typedef float f32x16 __attribute__((ext_vector_type(16)));
typedef unsigned u32;

#define MFMA16(a, b, c) __builtin_amdgcn_mfma_f32_16x16x32_f16((a), (b), (c), 0, 0, 0)
#define MFMA32(a, b, c) __builtin_amdgcn_mfma_f32_32x32x16_f16((a), (b), (c), 0, 0, 0)

#define QSCL 0.18033688011f /* 0.125 * log2(e): scores computed in log2 domain */

#define WAITV(N) asm volatile("s_waitcnt vmcnt(" #N ")" ::: "memory")
#define BAR()                          \
  {                                    \
    __builtin_amdgcn_s_barrier();      \
    __builtin_amdgcn_sched_barrier(0); \
  }

// async global->LDS, 16B per lane; dst wave-uniform base (HW adds lane*16)
__device__ __forceinline__ void gll16(const void* g, void* l) {
  __builtin_amdgcn_global_load_lds(
      (__attribute__((address_space(1))) unsigned int*)(void*)(g),
      (__attribute__((address_space(3))) unsigned int*)(l), 16, 0, 0);
}

// raw v_exp_f32 (input already in log2 domain)
__device__ __forceinline__ float ex2(float x) {
  float r;
  asm("v_exp_f32 %0, %1" : "=v"(r) : "v"(x));
  return r;
}

// v_permlane32_swap_b32: a' = [lo: a_lo | hi: b_lo], b' = [lo: a_hi | hi: b_hi]
__device__ __forceinline__ void plswap(u32& a, u32& b) {
  asm("s_nop 1\n\tv_permlane32_swap_b32 %0, %1\n\ts_nop 1" : "+v"(a), "+v"(b));
}

__device__ __forceinline__ u32 pk16(float lo, float hi) {
  __fp16 h2[2];
  *(decltype(__builtin_amdgcn_cvt_pkrtz(0.f, 0.f))*)h2 =
      __builtin_amdgcn_cvt_pkrtz(lo, hi);
  return *(u32*)h2;
}

// ---------------- fused prep: x->f16 + 4 weight transposes ----------------
__global__ void k_prep(const float* __restrict__ x, f16* __restrict__ xb,
                       const float* __restrict__ wq, const float* __restrict__ wk,
                       const float* __restrict__ wv, const float* __restrict__ wo,
                       f16* __restrict__ wqkvT, f16* __restrict__ woT) {
  __shared__ float tile[64][65];
  const int bid = blockIdx.x;
  if (bid < 4096) {  // x conversion, 4 floats/thread
    const int i = bid * 256 + threadIdx.x;
    float4 v = reinterpret_cast<const float4*>(x)[i];
    f16x4 o = {(f16)v.x, (f16)v.y, (f16)v.z, (f16)v.w};
    reinterpret_cast<f16x4*>(xb)[i] = o;
    return;
  }
  const int tb = bid - 4096;   // 0..1023
  const int which = tb >> 8;   // 0..3 : wq, wk, wv, wo
  const int bidx = tb & 255;
  const float* src = which == 0 ? wq : which == 1 ? wk : which == 2 ? wv : wo;
  f16* dst = which == 0 ? wqkvT
             : which == 1 ? wqkvT + (size_t)1024 * 1024
             : which == 2 ? wqkvT + (size_t)2048 * 1024
                          : woT;
  const int bc = bidx & 15, br = bidx >> 4;
  const int r0 = br << 6, c0 = bc << 6;
  const int tr = threadIdx.x >> 6, tc = threadIdx.x & 63;
#pragma unroll
  for (int p = 0; p < 16; ++p)
    tile[p * 4 + tr][tc] = src[(size_t)(r0 + p * 4 + tr) * 1024 + c0 + tc];
  __syncthreads();
#pragma unroll
  for (int p = 0; p < 16; ++p)
    dst[(size_t)(c0 + p * 4 + tr) * 1024 + r0 + tc] = (f16)tile[tc][p * 4 + tr];
}

// ---------------- GEMM: C[M][N] = A[M][Kd] * Bt[N][Kd]^T ----------------
// 128 x (NFR*32) tile, 4 waves (2x2), wave does 64 x (NFR*16).
// LDS chunk-swizzle: LDS(row, chunk) holds global(row, chunk ^ ((row>>1)&3))
// via pre-swizzled gll16 SOURCE (dest linear); reads XOR the same term.
// PAIR=0: triple-buffered BK=32 steps, counted vmcnt (proven).
// PAIR=1: 4 buffers, 2 K-steps per barrier interval.
// MODE 0 (NFR=4): QKV epilogue (bias, Q*QSCL, V transposed, all f16).
// MODE 1 (NFR=2): out-proj fp32 (128x64 tile -> 512 blocks).
template <int MODE, int NFR, int PAIR>
__global__ __launch_bounds__(256, 3) void k_gemm(
    const f16* __restrict__ A, const f16* __restrict__ Bt, int nbm, int Kd,
    const float* __restrict__ bias0, const float* __restrict__ bias1,
    const float* __restrict__ bias2,
    f16* __restrict__ Qo, f16* __restrict__ Ko, f16* __restrict__ Vo,
    float* __restrict__ Fo) {
  constexpr int TSZ = 8192 + NFR * 2048;  // per-buffer: A 8KB | B NFR*2KB
  constexpr int NBUF = PAIR ? 4 : 3;
  __shared__ __align__(16) char smem[NBUF * TSZ];
  const int tid = threadIdx.x;
  const int wid = tid >> 6, lane = tid & 63;
  const int r = lane & 15, t = lane >> 4;
  const int bm = blockIdx.x % nbm, bn = blockIdx.x / nbm;
  const int m0 = bm << 7, n0 = bn * (NFR * 32);
  const int wr = wid >> 1, wc = wid & 1;

  const f32x4 vz = {0.f, 0.f, 0.f, 0.f};
  f32x4 acc[4][NFR];
#pragma unroll
  for (int m = 0; m < 4; ++m)
#pragma unroll
    for (int n = 0; n < NFR; ++n) acc[m][n] = vz;

  const int srow = tid >> 2;  // staged row 0..63 (+64 on second issue)
  // chunk pre-swizzle: LDS chunk (tid&3) receives global chunk ^(srow>>1 &3)
  const int scb = (((tid & 3) ^ ((tid >> 3) & 3)) << 4);
  const size_t ldb = (size_t)Kd * 2;
  const char* Ab = (const char*)A + (size_t)m0 * ldb + scb;
  const char* Bb = (const char*)Bt + (size_t)n0 * ldb + scb;

  auto issue = [&](int kt, int buf) {
    const size_t kb = (size_t)kt << 6;
    char* base = smem + buf * TSZ;
    gll16(Ab + (size_t)srow * ldb + kb, base + wid * 1024);
    gll16(Ab + (size_t)(srow + 64) * ldb + kb, base + 4096 + wid * 1024);
    gll16(Bb + (size_t)srow * ldb + kb, base + 8192 + wid * 1024);
    if (NFR == 4)
      gll16(Bb + (size_t)(srow + 64) * ldb + kb, base + 8192 + 4096 + wid * 1024);
  };

  const int swz = ((r >> 1) & 3) << 4;  // read-side chunk swizzle (bytes)

  auto comp = [&](int buf) {
    const char* base = smem + buf * TSZ;
    f16x8 af[4], bg[NFR];
#pragma unroll
    for (int m = 0; m < 4; ++m)
      af[m] = *(const f16x8*)(base + ((wr * 64 + m * 16 + r) * 64 +
                                      ((t * 16) ^ swz)));
#pragma unroll
    for (int n = 0; n < NFR; ++n)
      bg[n] = *(const f16x8*)(base + 8192 +
                              ((wc * (NFR * 16) + n * 16 + r) * 64 +
                               ((t * 16) ^ swz)));
    __builtin_amdgcn_s_setprio(1);
#pragma unroll
    for (int m = 0; m < 4; ++m)
#pragma unroll
      for (int n = 0; n < NFR; ++n) acc[m][n] = MFMA16(af[m], bg[n], acc[m][n]);
    __builtin_amdgcn_s_setprio(0);
  };

  const int nk = Kd >> 5;  // 32
  if (PAIR) {
    // pair-wise: 4 bufs, step s -> buf s&3; one barrier per 2 K-steps
    issue(0, 0);
    issue(1, 1);
    const int nsup = nk >> 1;
    for (int T = 0; T < nsup; ++T) {
      WAITV(0);  // own pair T landed (issued a full super-step ago)
      BAR();     // all waves' pair T visible; pair T-1 bufs free
      if (T + 1 < nsup) {
        issue(2 * T + 2, (2 * T + 2) & 3);
        issue(2 * T + 3, (2 * T + 3) & 3);
      }
      comp((2 * T) & 3);
      comp((2 * T + 1) & 3);
    }
  } else {
    issue(0, 0);
    issue(1, 1);
    int b = 0, bi = 2;
    for (int kt = 0; kt < nk; ++kt) {
      if (kt + 1 < nk) {
        if (NFR == 4) {
          WAITV(4);
        } else {
          WAITV(3);
        }
      } else {
        WAITV(0);
      }
      BAR();
      if (kt + 2 < nk) issue(kt + 2, bi);
      comp(b);
      b = (b == 2) ? 0 : b + 1;
      bi = (bi == 2) ? 0 : bi + 1;
    }
  }

#pragma unroll
  for (int m = 0; m < 4; ++m) {
    const int row0 = m0 + wr * 64 + m * 16 + t * 4;
#pragma unroll
    for (int n = 0; n < NFR; ++n) {
      const int gc = n0 + wc * (NFR * 16) + n * 16 + r;
      if (MODE == 0) {
        const float b2 = gc < 1024 ? bias0[gc]
                                   : (gc < 2048 ? bias1[gc - 1024] : bias2[gc - 2048]);
        float v[4];
#pragma unroll
        for (int i = 0; i < 4; ++i) v[i] = acc[m][n][i] + b2;
        if (gc < 1024) {  // Q, pre-scaled into log2 domain
#pragma unroll
          for (int i = 0; i < 4; ++i)
            Qo[(size_t)(row0 + i) * 1024 + gc] = (f16)(v[i] * QSCL);
        } else if (gc < 2048) {  // K natural layout
#pragma unroll
          for (int i = 0; i < 4; ++i)
            Ko[(size_t)(row0 + i) * 1024 + (gc - 1024)] = (f16)v[i];
        } else {  // V transposed: Vt[hk][s] f16
          f16x4 pk = {(f16)v[0], (f16)v[1], (f16)v[2], (f16)v[3]};
          *(f16x4*)(Vo + (size_t)(gc - 2048) * 4096 + row0) = pk;
        }
      } else {
        const float b2 = bias0[gc];
#pragma unroll
        for (int i = 0; i < 4; ++i)
          Fo[(size_t)(row0 + i) * 1024 + gc] = acc[m][n][i] + b2;
      }
    }
  }
}

// ---- fattn work table: 48 items per head, descending super-iter count ----
// ch: 0 = kv-chunk 0 (lower kv half, no diagonal), 1 = kv-chunk 1 (upper kv
// half incl. diagonal), 2 = unsplit (qt <= 15 causal).
// Causal lens: ch2 = qt+1; ch0 = ceil((qt+1)/2); ch1 = floor((qt+1)/2).
// Descending (LPT) order bounds makespan near total/slots.
__constant__ unsigned char g_qt[48] = {
    15, 30, 31, 31, 14, 28, 29, 29, 30, 13, 26, 27, 27, 28, 12, 24,
    25, 25, 26, 11, 22, 23, 23, 24, 10, 20, 21, 21, 22, 9,  18, 19,
    19, 20, 8,  16, 17, 17, 18, 7,  16, 6,  5,  4,  3,  2,  1,  0};
__constant__ unsigned char g_ch[48] = {
    2, 0, 0, 1, 2, 0, 0, 1, 1, 2, 0, 0, 1, 1, 2, 0,
    0, 1, 1, 2, 0, 0, 1, 1, 2, 0, 0, 1, 1, 2, 0, 0,
    1, 1, 2, 0, 0, 1, 1, 2, 1, 2, 2, 2, 2, 2, 2, 2};

// ---------------- flash attention (32x32 MFMA, per-tile 3-buf ring) ------
// Round-7 re-analysis: round 6's split failed to help because LDS (66 KB)
// capped residency at 2 blocks/CU — the 768-block grid ran as 512 resident
// + 256 serialized tail, so makespan stayed ~33 iters. Occupancy ~27-30%
// across ALL rounds = that cap. THIS ROUND (all f16, no precision change):
//  * 3-buffer per-tile ring (16KB/tile), LDS 50176 B -> 3 blocks/CU.
//  * kv-split + LPT 768-grid + two-phase k_fix merge (round-6 machinery,
//    proven correct) -> all blocks co-resident, makespan ~17 iters.
//  * single-tile compute body (round-2's, 56 VGPR) + launch_bounds(512,6)
//    (VGPR cap 85) so 24 waves/CU = 6/SIMD fit.
// Ring protocol: prologue issue tiles j0,j0+1 -> bufs 0,1. Iter jj:
//   BAR (all waves done with tile jj-1 -> buf (jj+2)%3 free)
//   -> issue tile jj+2 into (jj+2)%3 -> WAITV(4) (tile jj landed; jj+1,
//   jj+2 in flight, 2 gll16 each) -> compute tile jj from buf jj%3.
// Tail: WAITV(2) then WAITV(0). Lookahead-2 preserves the issue-to-use
// distance of the proven pair scheme.
__global__ __launch_bounds__(512, 6) void k_fattn(
    const f16* __restrict__ Q, const f16* __restrict__ Kb,
    const f16* __restrict__ Vt, f16* __restrict__ vals,
    const int* __restrict__ causp, f16* __restrict__ part_o,
    float* __restrict__ part_ls) {
  __shared__ uint4 ldsv[3136];  // 50176 B: 3 x 16KB tile bufs | 1KB ls
  char* lds = (char*)ldsv;
  const int tid = threadIdx.x;
  const int W = tid >> 6, lane = tid & 63;
  const int l31 = lane & 31, hi = lane >> 5;
  const int wq = W >> 1, wkv = W & 1;
  const int h = blockIdx.x & 15;
  const int it = blockIdx.x >> 4;  // 0..47
  const int qt = g_qt[it];
  const int ch = g_ch[it];
  const int cz = *causp;
  int Tstart, tlen;  // super-iter (pair) units, as round 6
  if (ch == 2) {
    Tstart = 0;
    tlen = cz ? qt + 1 : 32;
  } else if (ch == 0) {
    Tstart = 0;
    tlen = cz ? (qt + 2) >> 1 : 16;
  } else {
    Tstart = cz ? (qt + 2) >> 1 : 16;
    tlen = cz ? (qt + 1) >> 1 : 16;
  }
  const int j0 = 2 * Tstart;          // first kv tile index
  const int n = 2 * tlen - 1;         // last local tile index (>=1)
  const int dw = wq - wkv;            // -1..3
  const int jmax_w = cz ? (2 * qt + (dw >= 2 ? 1 : 0) - (dw < 0 ? 1 : 0)) : 63;
  const bool maskd = cz && ((dw & 1) == 0);  // dw == 0 or 2: diagonal tile

  // Q B-frags: col q = 128qt + 32wq + l31, k = d = 16s + 8hi + 0..7
  const size_t qrow = (size_t)((qt << 7) + (wq << 5) + l31) * 1024 + h * 64;
  f16x8 qf[4];
#pragma unroll
  for (int s = 0; s < 4; ++s) qf[s] = *(const f16x8*)(Q + qrow + 16 * s + 8 * hi);

  f32x16 o0, o1, zv;
#pragma unroll
  for (int e = 0; e < 16; ++e) { o0[e] = 0.f; o1[e] = 0.f; zv[e] = 0.f; }
  float Ls = 0.f;  // running row-sum for q = 32*wq + l31 (this wkv half)

  // staging: wave W stages K rows [8W,8W+8) + V rows [8W,8W+8): 2 gll16/tile.
  // Source pre-swizzled: chunk sch reads global chunk sch ^ (row&7).
  const int srw = lane >> 3, sch = lane & 7;
  const int ssw = (sch ^ srw) << 3;  // f16-element offset within row
  const char* kcur =
      (const char*)(Kb + (size_t)(8 * W + srw) * 1024 + h * 64 + ssw) +
      (size_t)j0 * 131072;  // 64 K-rows * 2048 B per tile
  const char* vcur =
      (const char*)(Vt + (size_t)(h * 64 + 8 * W + srw) * 4096 + ssw) +
      (size_t)j0 * 128;  // 64 cols * 2 B per tile

  auto issue = [&](int buf) {
    char* base = lds + buf * 16384 + W * 1024;
    gll16(kcur, base);
    gll16(vcur, base + 8192);
    kcur += (size_t)64 * 2048;  // next kv tile (64 K rows)
    vcur += 128;                // next kv tile (64 cols * 2B)
  };

  // LDS read offsets
  const int krow = (wkv << 5) + l31, ksw = krow & 7;
  const int vsw = l31 & 7;  // V rows l31 and 32+l31 share row&7

  // one kv-tile compute: QK -> mask -> exp -> rowsum -> pack/swap -> PV
  auto tilec = [&](int j, const char* Kbase) {
    if (j > jmax_w) return;
    const char* Vbase = Kbase + 8192;
    __builtin_amdgcn_s_setprio(1);
    const f16x8 af0 =
        *(const f16x8*)(Kbase + krow * 128 + ((hi ^ ksw) << 4));
    f32x16 sc = MFMA32(af0, qf[0], zv);  // C-init from loop-invariant zeros
#pragma unroll
    for (int s = 1; s < 4; ++s) {
      const f16x8 af =
          *(const f16x8*)(Kbase + krow * 128 + (((2 * s + hi) ^ ksw) << 4));
      sc = MFMA32(af, qf[s], sc);
    }
    __builtin_amdgcn_s_setprio(0);
    if (maskd && j == jmax_w) {  // diagonal: mask kv_local > q_local
#pragma unroll
      for (int e = 0; e < 16; ++e) {
        const int kvr = (e & 3) + 8 * (e >> 2) + 4 * hi;
        if (kvr > l31) sc[e] = -1e9f;
      }
    }
    float p[16];
#pragma unroll
    for (int e = 0; e < 16; ++e) p[e] = ex2(sc[e]);
    // VALU row-sum: lane covers 16 kv rows of q=l31; cross-half via plswap
    {
      float s0 = (p[0] + p[1]) + (p[2] + p[3]);
      float s1 = (p[4] + p[5]) + (p[6] + p[7]);
      float s2 = (p[8] + p[9]) + (p[10] + p[11]);
      float s3 = (p[12] + p[13]) + (p[14] + p[15]);
      float s = (s0 + s1) + (s2 + s3);
      union { float f; u32 u; } ua, ub;
      ua.f = s; ub.f = s;
      plswap(ua.u, ub.u);
      Ls += ua.f + ub.f;
    }
    // two 16-kv windows -> PV A-frags via pack + permlane32_swap
#pragma unroll
    for (int ks = 0; ks < 2; ++ks) {
      u32 c0 = pk16(p[8 * ks + 0], p[8 * ks + 1]);
      u32 c1 = pk16(p[8 * ks + 2], p[8 * ks + 3]);
      u32 c2 = pk16(p[8 * ks + 4], p[8 * ks + 5]);
      u32 c3 = pk16(p[8 * ks + 6], p[8 * ks + 7]);
      plswap(c0, c2);
      plswap(c1, c3);
      union { u32 w[4]; f16x8 v; } pa;
      pa.w[0] = c0; pa.w[1] = c1; pa.w[2] = c2; pa.w[3] = c3;
      const int cl = 4 * wkv + 2 * ks + hi;
      const f16x8 vf0 = *(const f16x8*)(Vbase + l31 * 128 + ((cl ^ vsw) << 4));
      const f16x8 vf1 =
          *(const f16x8*)(Vbase + (32 + l31) * 128 + ((cl ^ vsw) << 4));
      __builtin_amdgcn_s_setprio(1);
      o0 = MFMA32(pa.v, vf0, o0);
      o1 = MFMA32(pa.v, vf1, o1);
      __builtin_amdgcn_s_setprio(0);
    }
  };

  // prologue: stage tiles j0, j0+1 into bufs 0, 1 (n >= 1 always)
  issue(0);
  issue(1);

  for (int jj = 0; jj <= n; ++jj) {
    BAR();  // all waves done with tile jj-1 (buf (jj+2)%3 now free)
    if (jj + 2 <= n) {
      issue((jj + 2) % 3);
      WAITV(4);  // tile jj landed; jj+1, jj+2 in flight
    } else if (jj + 1 <= n) {
      WAITV(2);  // tile jj landed; jj+1 in flight
    } else {
      WAITV(0);
    }
    tilec(j0 + jj, lds + (jj % 3) * 16384);
  }
  __syncthreads();  // all compute done before LDS reuse

  // epilogue: merge wkv halves through LDS; then direct store (ch==2) or
  // disjoint partial write (ch 0/1) for the k_fix merge kernel.
  float* obuf = (float*)lds;             // 4 x 8KB (per wq)
  float* lsbuf = (float*)(lds + 49152);  // 4 wq x 2 wkv x 32 q f32
  if (hi == 0) lsbuf[wq * 64 + wkv * 32 + l31] = Ls;
  if (wkv == 1) {
    float* base = obuf + wq * 2048;
#pragma unroll
    for (int dblk = 0; dblk < 2; ++dblk)
#pragma unroll
      for (int rg = 0; rg < 4; ++rg) {
        const f32x16& o = dblk ? o1 : o0;
        f32x4 t = {o[rg * 4 + 0], o[rg * 4 + 1], o[rg * 4 + 2], o[rg * 4 + 3]};
        *(f32x4*)(base + ((dblk * 4 + rg) * 64 + lane) * 4) = t;
      }
  }
  __syncthreads();

  float lst[16];
  const bool writer = (wkv == 0);
  if (writer) {
    float* base = obuf + wq * 2048;
#pragma unroll
    for (int dblk = 0; dblk < 2; ++dblk)
#pragma unroll
      for (int rg = 0; rg < 4; ++rg) {
        f32x4 t = *(f32x4*)(base + ((dblk * 4 + rg) * 64 + lane) * 4);
        f32x16& o = dblk ? o1 : o0;
#pragma unroll
        for (int i = 0; i < 4; ++i) o[rg * 4 + i] += t[i];
      }
#pragma unroll
    for (int e = 0; e < 16; ++e) {
      const int q = (e & 3) + 8 * (e >> 2) + 4 * hi;
      lst[e] = lsbuf[wq * 64 + q] + lsbuf[wq * 64 + 32 + q];
    }
  }

  if (ch == 2) {  // unsplit: normalize + store f16 vals
    if (writer) {
      const int row0 = (qt << 7) + (wq << 5);
#pragma unroll
      for (int dblk = 0; dblk < 2; ++dblk) {
        const f32x16& o = dblk ? o1 : o0;
        const int col = h * 64 + 32 * dblk + l31;
#pragma unroll
        for (int e = 0; e < 16; ++e) {
          const int rr = row0 + (e & 3) + 8 * (e >> 2) + 4 * hi;
          vals[(size_t)rr * 1024 + col] = (f16)(o[e] / lst[e]);
        }
      }
    }
    return;
  }

  // split chunk: write own disjoint partial (no inter-block communication)
  if (writer) {
    const int tix = h * 16 + (qt - 16);        // 0..255
    const int slot = (tix << 1) | ch;          // 0..511
    f16* po = part_o + (size_t)slot * 8192;    // [128][64] f16
    float* pl = part_ls + slot * 128;          // [128] f32
#pragma unroll
    for (int dblk = 0; dblk < 2; ++dblk) {
      const f32x16& o = dblk ? o1 : o0;
      const int col = 32 * dblk + l31;
#pragma unroll
      for (int e = 0; e < 16; ++e) {
        const int rr = 32 * wq + (e & 3) + 8 * (e >> 2) + 4 * hi;
        po[rr * 64 + col] = (f16)o[e];
      }
    }
    if (l31 == 0) {
#pragma unroll
      for (int e = 0; e < 16; ++e) {
        const int q = (e & 3) + 8 * (e >> 2) + 4 * hi;
        pl[32 * wq + q] = lst[e];
      }
    }
  }
}

// ---------------- fixup: merge split-tile partials -> vals ----------------
// 256 blocks (one per split tile tix = h*16 + (qt-16)), 256 threads.
// vals[qt*128 + r][h*64 + c] = (po0[r][c] + po1[r][c]) / (ls0[r] + ls1[r]).
__global__ __launch_bounds__(256) void k_fix(const f16* __restrict__ part_o,
                                             const float* __restrict__ part_ls,
                                             f16* __restrict__ vals) {
  const int tix = blockIdx.x;  // 0..255
  const int h = tix >> 4, qt = 16 + (tix & 15);
  const int t = threadIdx.x;
  const int row = t >> 1, c0 = (t & 1) * 32;
  const f16* po0 = part_o + (((size_t)tix << 1) | 0) * 8192;
  const f16* po1 = part_o + (((size_t)tix << 1) | 1) * 8192;
  const float ls = part_ls[((tix << 1) | 0) * 128 + row] +
                   part_ls[((tix << 1) | 1) * 128 + row];
  const float inv = 1.0f / ls;
  const f16* a = po0 + row * 64 + c0;
  const f16* b = po1 + row * 64 + c0;
  f16* d = vals + (size_t)((qt << 7) + row) * 1024 + h * 64 + c0;
#pragma unroll
  for (int i = 0; i < 4; ++i) {
    f16x8 va = *(const f16x8*)(a + 8 * i);
    f16x8 vb = *(const f16x8*)(b + 8 * i);
    f16x8 vo;
#pragma unroll
    for (int j = 0; j < 8; ++j)
      vo[j] = (f16)(((float)va[j] + (float)vb[j]) * inv);
    *(f16x8*)(d + 8 * i) = vo;
  }
}

extern "C" void kernel_launch(void* const* d_in, const int* in_sizes, int n_in,
                              void* d_out, int out_size, void* d_ws, size_t ws_size,
                              hipStream_t stream) {
  const float* x = (const float*)d_in[0];
  const float* wq = (const float*)d_in[1];
  const float* bq = (const float*)d_in[2];
  const float* wk = (const float*)d_in[3];
  const float* bk = (const float*)d_in[4];
  const float* wv = (const float*)d_in[5];
  const float* bv = (const float*)d_in[6];
  const float* wo = (const float*)d_in[7];
  const float* bo = (const float*)d_in[8];
  const int* caus = (const int*)d_in[9];
  float* out = (float*)d_out;

  // workspace layout (fp16): 48 MiB total
  f16* xb = (f16*)d_ws;                    // [4096][1024]
  f16* wqkvT = xb + (size_t)4096 * 1024;   // [3072][1024] (n, d)
  f16* woT = wqkvT + (size_t)3072 * 1024;  // [1024][1024] (d, hk)
  f16* Qb = woT + (size_t)1024 * 1024;     // [4096][1024], log2-domain scaled
  f16* Kbuf = Qb + (size_t)4096 * 1024;    // [4096][1024]
  f16* Vt = Kbuf + (size_t)4096 * 1024;    // [1024][4096] (hk, s)
  f16* vals = Vt + (size_t)4096 * 1024;    // [4096][1024]

  // fattn split-tile scratch overlays regions dead after the QKV GEMM:
  f16* part_o = xb;                // 512 slots x [128][64] f16 = 8 MB (= xb)
  float* part_ls = (float*)wqkvT;  // 512 slots x [128] f32 = 256 KB

  k_prep<<<5120, 256, 0, stream>>>(x, xb, wq, wk, wv, wo, wqkvT, woT);
  k_gemm<0, 4, 0><<<32 * 24, 256, 0, stream>>>(xb, wqkvT, 32, 1024, bq, bk, bv,
                                               Qb, Kbuf, Vt, nullptr);
  k_fattn<<<768, 512, 0, stream>>>(Qb, Kbuf, Vt, vals, caus, part_o, part_ls);
  k_fix<<<256, 256, 0, stream>>>(part_o, part_ls, vals);
  k_gemm<1, 2, 1><<<32 * 16, 256, 0, stream>>>(vals, woT, 32, 1024, bo, nullptr,
                                               nullptr, nullptr, nullptr,
                                               nullptr, out);
}

// Round 9
// 117.491 us; speedup vs baseline: 1.3868x; 1.3868x over previous
//
#include <hip/hip_runtime.h>

typedef _Float16 f16;
typedef f16 f16x8 __attribute__((ext_vector_type(8)));
typedef f16 f16x4 __attribute__((ext_vector_type(4)));
typedef float f32x2 __attribute__((ext_vector_type(2)));
typedef float f32x4 __attribute__((ext_vector_type(4)));
typedef float f32x16 __attribute__((ext_vector_type(16)));
typedef unsigned u32;

#define MFMA16(a, b, c) __builtin_amdgcn_mfma_f32_16x16x32_f16((a), (b), (c), 0, 0, 0)
#define MFMA32(a, b, c) __builtin_amdgcn_mfma_f32_32x32x16_f16((a), (b), (c), 0, 0, 0)

#define QSCL 0.18033688011f /* 0.125 * log2(e): scores computed in log2 domain */

#define WAITV(N) asm volatile("s_waitcnt vmcnt(" #N ")" ::: "memory")
#define BAR()                          \
  {                                    \
    __builtin_amdgcn_s_barrier();      \
    __builtin_amdgcn_sched_barrier(0); \
  }

// async global->LDS, 16B per lane; dst wave-uniform base (HW adds lane*16)
__device__ __forceinline__ void gll16(const void* g, void* l) {
  __builtin_amdgcn_global_load_lds(
      (__attribute__((address_space(1))) unsigned int*)(void*)(g),
      (__attribute__((address_space(3))) unsigned int*)(l), 16, 0, 0);
}

// raw v_exp_f32 (input already in log2 domain)
__device__ __forceinline__ float ex2(float x) {
  float r;
  asm("v_exp_f32 %0, %1" : "=v"(r) : "v"(x));
  return r;
}

// v_permlane32_swap_b32: a' = [lo: a_lo | hi: b_lo], b' = [lo: a_hi | hi: b_hi]
__device__ __forceinline__ void plswap(u32& a, u32& b) {
  asm("s_nop 1\n\tv_permlane32_swap_b32 %0, %1\n\ts_nop 1" : "+v"(a), "+v"(b));
}

// two independent permlane32_swaps sharing one hazard window (saves 2 s_nop)
__device__ __forceinline__ void plswap2(u32& a, u32& b, u32& c, u32& d) {
  asm("s_nop 1\n\tv_permlane32_swap_b32 %0, %1\n\tv_permlane32_swap_b32 %2, %3\n\ts_nop 1"
      : "+v"(a), "+v"(b), "+v"(c), "+v"(d));
}

__device__ __forceinline__ u32 pk16(float lo, float hi) {
  __fp16 h2[2];
  *(decltype(__builtin_amdgcn_cvt_pkrtz(0.f, 0.f))*)h2 =
      __builtin_amdgcn_cvt_pkrtz(lo, hi);
  return *(u32*)h2;
}

// ---------------- fused prep: x->f16 + 4 weight transposes ----------------
__global__ void k_prep(const float* __restrict__ x, f16* __restrict__ xb,
                       const float* __restrict__ wq, const float* __restrict__ wk,
                       const float* __restrict__ wv, const float* __restrict__ wo,
                       f16* __restrict__ wqkvT, f16* __restrict__ woT) {
  __shared__ float tile[64][65];
  const int bid = blockIdx.x;
  if (bid < 4096) {  // x conversion, 4 floats/thread
    const int i = bid * 256 + threadIdx.x;
    float4 v = reinterpret_cast<const float4*>(x)[i];
    f16x4 o = {(f16)v.x, (f16)v.y, (f16)v.z, (f16)v.w};
    reinterpret_cast<f16x4*>(xb)[i] = o;
    return;
  }
  const int tb = bid - 4096;   // 0..1023
  const int which = tb >> 8;   // 0..3 : wq, wk, wv, wo
  const int bidx = tb & 255;
  const float* src = which == 0 ? wq : which == 1 ? wk : which == 2 ? wv : wo;
  f16* dst = which == 0 ? wqkvT
             : which == 1 ? wqkvT + (size_t)1024 * 1024
             : which == 2 ? wqkvT + (size_t)2048 * 1024
                          : woT;
  const int bc = bidx & 15, br = bidx >> 4;
  const int r0 = br << 6, c0 = bc << 6;
  const int tr = threadIdx.x >> 6, tc = threadIdx.x & 63;
#pragma unroll
  for (int p = 0; p < 16; ++p)
    tile[p * 4 + tr][tc] = src[(size_t)(r0 + p * 4 + tr) * 1024 + c0 + tc];
  __syncthreads();
#pragma unroll
  for (int p = 0; p < 16; ++p)
    dst[(size_t)(c0 + p * 4 + tr) * 1024 + r0 + tc] = (f16)tile[tc][p * 4 + tr];
}

// ---------------- GEMM: C[M][N] = A[M][Kd] * Bt[N][Kd]^T ----------------
// 128 x (NFR*32) tile, 4 waves (2x2), wave does 64 x (NFR*16).
// LDS chunk-swizzle: LDS(row, chunk) holds global(row, chunk ^ ((row>>1)&3))
// via pre-swizzled gll16 SOURCE (dest linear); reads XOR the same term.
// PAIR=0: triple-buffered BK=32 steps, counted vmcnt (proven).
// PAIR=1: 4 buffers, 2 K-steps per barrier interval.
// MODE 0 (NFR=4): QKV epilogue (bias, Q*QSCL, V transposed).
// MODE 1 (NFR=2): out-proj fp32 (128x64 tile -> 512 blocks).
template <int MODE, int NFR, int PAIR>
__global__ __launch_bounds__(256, 3) void k_gemm(
    const f16* __restrict__ A, const f16* __restrict__ Bt, int nbm, int Kd,
    const float* __restrict__ bias0, const float* __restrict__ bias1,
    const float* __restrict__ bias2,
    f16* __restrict__ Qo, f16* __restrict__ Ko, f16* __restrict__ Vo,
    float* __restrict__ Fo) {
  constexpr int TSZ = 8192 + NFR * 2048;  // per-buffer: A 8KB | B NFR*2KB
  constexpr int NBUF = PAIR ? 4 : 3;
  __shared__ __align__(16) char smem[NBUF * TSZ];
  const int tid = threadIdx.x;
  const int wid = tid >> 6, lane = tid & 63;
  const int r = lane & 15, t = lane >> 4;
  const int bm = blockIdx.x % nbm, bn = blockIdx.x / nbm;
  const int m0 = bm << 7, n0 = bn * (NFR * 32);
  const int wr = wid >> 1, wc = wid & 1;

  const f32x4 vz = {0.f, 0.f, 0.f, 0.f};
  f32x4 acc[4][NFR];
#pragma unroll
  for (int m = 0; m < 4; ++m)
#pragma unroll
    for (int n = 0; n < NFR; ++n) acc[m][n] = vz;

  const int srow = tid >> 2;  // staged row 0..63 (+64 on second issue)
  // chunk pre-swizzle: LDS chunk (tid&3) receives global chunk ^(srow>>1 &3)
  const int scb = (((tid & 3) ^ ((tid >> 3) & 3)) << 4);
  const size_t ldb = (size_t)Kd * 2;
  const char* Ab = (const char*)A + (size_t)m0 * ldb + scb;
  const char* Bb = (const char*)Bt + (size_t)n0 * ldb + scb;

  auto issue = [&](int kt, int buf) {
    const size_t kb = (size_t)kt << 6;
    char* base = smem + buf * TSZ;
    gll16(Ab + (size_t)srow * ldb + kb, base + wid * 1024);
    gll16(Ab + (size_t)(srow + 64) * ldb + kb, base + 4096 + wid * 1024);
    gll16(Bb + (size_t)srow * ldb + kb, base + 8192 + wid * 1024);
    if (NFR == 4)
      gll16(Bb + (size_t)(srow + 64) * ldb + kb, base + 8192 + 4096 + wid * 1024);
  };

  const int swz = ((r >> 1) & 3) << 4;  // read-side chunk swizzle (bytes)

  auto comp = [&](int buf) {
    const char* base = smem + buf * TSZ;
    f16x8 af[4], bg[NFR];
#pragma unroll
    for (int m = 0; m < 4; ++m)
      af[m] = *(const f16x8*)(base + ((wr * 64 + m * 16 + r) * 64 +
                                      ((t * 16) ^ swz)));
#pragma unroll
    for (int n = 0; n < NFR; ++n)
      bg[n] = *(const f16x8*)(base + 8192 +
                              ((wc * (NFR * 16) + n * 16 + r) * 64 +
                               ((t * 16) ^ swz)));
    __builtin_amdgcn_s_setprio(1);
#pragma unroll
    for (int m = 0; m < 4; ++m)
#pragma unroll
      for (int n = 0; n < NFR; ++n) acc[m][n] = MFMA16(af[m], bg[n], acc[m][n]);
    __builtin_amdgcn_s_setprio(0);
  };

  const int nk = Kd >> 5;  // 32
  if (PAIR) {
    // pair-wise: 4 bufs, step s -> buf s&3; one barrier per 2 K-steps
    issue(0, 0);
    issue(1, 1);
    const int nsup = nk >> 1;
    for (int T = 0; T < nsup; ++T) {
      WAITV(0);  // own pair T landed (issued a full super-step ago)
      BAR();     // all waves' pair T visible; pair T-1 bufs free
      if (T + 1 < nsup) {
        issue(2 * T + 2, (2 * T + 2) & 3);
        issue(2 * T + 3, (2 * T + 3) & 3);
      }
      comp((2 * T) & 3);
      comp((2 * T + 1) & 3);
    }
  } else {
    issue(0, 0);
    issue(1, 1);
    int b = 0, bi = 2;
    for (int kt = 0; kt < nk; ++kt) {
      if (kt + 1 < nk) {
        if (NFR == 4) {
          WAITV(4);
        } else {
          WAITV(3);
        }
      } else {
        WAITV(0);
      }
      BAR();
      if (kt + 2 < nk) issue(kt + 2, bi);
      comp(b);
      b = (b == 2) ? 0 : b + 1;
      bi = (bi == 2) ? 0 : bi + 1;
    }
  }

#pragma unroll
  for (int m = 0; m < 4; ++m) {
    const int row0 = m0 + wr * 64 + m * 16 + t * 4;
#pragma unroll
    for (int n = 0; n < NFR; ++n) {
      const int gc = n0 + wc * (NFR * 16) + n * 16 + r;
      if (MODE == 0) {
        const float b2 = gc < 1024 ? bias0[gc]
                                   : (gc < 2048 ? bias1[gc - 1024] : bias2[gc - 2048]);
        float v[4];
#pragma unroll
        for (int i = 0; i < 4; ++i) v[i] = acc[m][n][i] + b2;
        if (gc < 1024) {  // Q, pre-scaled into log2 domain
#pragma unroll
          for (int i = 0; i < 4; ++i)
            Qo[(size_t)(row0 + i) * 1024 + gc] = (f16)(v[i] * QSCL);
        } else if (gc < 2048) {  // K natural layout
#pragma unroll
          for (int i = 0; i < 4; ++i)
            Ko[(size_t)(row0 + i) * 1024 + (gc - 1024)] = (f16)v[i];
        } else {  // V transposed: Vt[hk][s]
          f16x4 pk = {(f16)v[0], (f16)v[1], (f16)v[2], (f16)v[3]};
          *(f16x4*)(Vo + (size_t)(gc - 2048) * 4096 + row0) = pk;
        }
      } else {
        const float b2 = bias0[gc];
#pragma unroll
        for (int i = 0; i < 4; ++i)
          Fo[(size_t)(row0 + i) * 1024 + gc] = acc[m][n][i] + b2;
      }
    }
  }
}

// ---------------- flash attention (32x32 MFMA, pair-wise barriers) -------
// ROUND-3 STRUCTURE EXACTLY (proven 52.8 us): grid 512, balanced pairing
// {31-i,i} (co-resident same-head blocks stream K/V as aligned prefixes ->
// FETCH 12.3MB, the L2-locality optimum; round 8 proved breaking this
// costs 2x), 4-buf pair scheme, QK(A),QK(B),fin(A),fin(B) pipeline, VALU
// row-sum. ROUND-9 CHANGE: VALU issue-slot reduction only (VALU issues ~3x
// MFMA cycles; VALUBusy 40% is the top pipe):
//  * exp results kept as f32x2 pairs -> row-sum via 7 packed v_pk_add_f32
//    (was 15 scalar adds)
//  * fused double-permlane32_swap sharing one hazard window (saves 2
//    s_nop per pack phase)
//  * 12 per-tile LDS read offsets hoisted to loop-invariant registers
__global__ __launch_bounds__(512, 4) void k_fattn(
    const f16* __restrict__ Q, const f16* __restrict__ Kb,
    const f16* __restrict__ Vt, f16* __restrict__ vals,
    const int* __restrict__ causp) {
  __shared__ uint4 ldsv[4128];  // 66048 B: 4 x 16KB KV bufs | ls scratch
  char* lds = (char*)ldsv;
  const int tid = threadIdx.x;
  const int W = tid >> 6, lane = tid & 63;
  const int l31 = lane & 31, hi = lane >> 5;
  const int wq = W >> 1, wkv = W & 1;
  const int h = blockIdx.x & 15;
  const int idx = blockIdx.x >> 4;  // 0..31
  const int qt = idx < 16 ? 31 - idx : idx - 16;  // co-resident pair: balance
  const int cz = *causp;
  const int Tmax = cz ? qt : 31;              // super-iters - 1 (2 tiles each)
  const int dw = wq - wkv;                    // -1..3
  const int jmax_w = cz ? (2 * qt + (dw >= 2 ? 1 : 0) - (dw < 0 ? 1 : 0)) : 63;
  const bool maskd = cz && ((dw & 1) == 0);  // dw == 0 or 2: diagonal tile

  // Q B-frags: col q = 128qt + 32wq + l31, k = d = 16s + 8hi + 0..7
  const size_t qrow = (size_t)((qt << 7) + (wq << 5) + l31) * 1024 + h * 64;
  f16x8 qf[4];
#pragma unroll
  for (int s = 0; s < 4; ++s) qf[s] = *(const f16x8*)(Q + qrow + 16 * s + 8 * hi);

  f32x16 o0, o1, zv;
#pragma unroll
  for (int e = 0; e < 16; ++e) { o0[e] = 0.f; o1[e] = 0.f; zv[e] = 0.f; }
  float Ls = 0.f;  // running row-sum for q = 32*wq + l31 (this wkv half)

  // staging: wave W stages K rows [8W,8W+8) + V rows [8W,8W+8): 2 gll16/tile.
  // Source pre-swizzled: chunk sch reads global chunk sch ^ (row&7).
  const int srw = lane >> 3, sch = lane & 7;
  const int ssw = (sch ^ srw) << 3;  // f16-element offset within row
  const char* kcur =
      (const char*)(Kb + (size_t)(8 * W + srw) * 1024 + h * 64 + ssw);
  const char* vcur =
      (const char*)(Vt + (size_t)(h * 64 + 8 * W + srw) * 4096 + ssw);

  auto issue = [&](int buf) {
    char* base = lds + buf * 16384 + W * 1024;
    gll16(kcur, base);
    gll16(vcur, base + 8192);
    kcur += (size_t)64 * 2048;  // next kv tile (64 K rows)
    vcur += 128;                // next kv tile (64 cols * 2B)
  };

  // LDS read offsets (ALL loop-invariant -> hoisted into registers)
  const int krow = (wkv << 5) + l31, ksw = krow & 7;
  const int vsw = l31 & 7;  // V rows l31 and 32+l31 share row&7
  int koff[4];
#pragma unroll
  for (int s = 0; s < 4; ++s)
    koff[s] = krow * 128 + (((2 * s + hi) ^ ksw) << 4);
  int voffA[2], voffB[2];
#pragma unroll
  for (int ks = 0; ks < 2; ++ks) {
    const int cl = 4 * wkv + 2 * ks + hi;
    voffA[ks] = l31 * 128 + ((cl ^ vsw) << 4);
    voffB[ks] = (32 + l31) * 128 + ((cl ^ vsw) << 4);
  }

  // QK^T chain for one tile: af frags loaded here (short live range so A's
  // and B's frags can share registers)
  auto qk = [&](const char* Kbase) -> f32x16 {
    f16x8 af[4];
#pragma unroll
    for (int s = 0; s < 4; ++s)
      af[s] = *(const f16x8*)(Kbase + koff[s]);
    __builtin_amdgcn_s_setprio(1);
    f32x16 sc = MFMA32(af[0], qf[0], zv);
#pragma unroll
    for (int s = 1; s < 4; ++s) sc = MFMA32(af[s], qf[s], sc);
    __builtin_amdgcn_s_setprio(0);
    return sc;
  };

  // finish one tile: mask -> exp -> rowsum (packed) -> pack/swap -> PV
  auto fin = [&](int j, const char* Kbase, f32x16& sc) {
    const char* Vbase = Kbase + 8192;
    if (maskd && j == jmax_w) {  // diagonal: mask kv_local > q_local
#pragma unroll
      for (int e = 0; e < 16; ++e) {
        const int kvr = (e & 3) + 8 * (e >> 2) + 4 * hi;
        if (kvr > l31) sc[e] = -1e9f;
      }
    }
    f32x2 p2[8];
#pragma unroll
    for (int e = 0; e < 8; ++e) {
      f32x2 t;
      t[0] = ex2(sc[2 * e]);
      t[1] = ex2(sc[2 * e + 1]);
      p2[e] = t;
    }
    // packed-pair row-sum: 7 v_pk_add_f32 + 1 scalar; cross-half via plswap
    {
      f32x2 a0 = p2[0] + p2[1];
      f32x2 a1 = p2[2] + p2[3];
      f32x2 a2 = p2[4] + p2[5];
      f32x2 a3 = p2[6] + p2[7];
      f32x2 b0 = a0 + a1;
      f32x2 b1 = a2 + a3;
      f32x2 c = b0 + b1;
      float s = c[0] + c[1];
      union { float f; u32 u; } ua, ub;
      ua.f = s; ub.f = s;
      plswap(ua.u, ub.u);
      Ls += ua.f + ub.f;
    }
    // two 16-kv windows -> PV A-frags via pack + fused double-permlane
#pragma unroll
    for (int ks = 0; ks < 2; ++ks) {
      u32 c0 = pk16(p2[4 * ks + 0][0], p2[4 * ks + 0][1]);
      u32 c1 = pk16(p2[4 * ks + 1][0], p2[4 * ks + 1][1]);
      u32 c2 = pk16(p2[4 * ks + 2][0], p2[4 * ks + 2][1]);
      u32 c3 = pk16(p2[4 * ks + 3][0], p2[4 * ks + 3][1]);
      plswap2(c0, c2, c1, c3);
      union { u32 w[4]; f16x8 v; } pa;
      pa.w[0] = c0; pa.w[1] = c1; pa.w[2] = c2; pa.w[3] = c3;
      const f16x8 vf0 = *(const f16x8*)(Vbase + voffA[ks]);
      const f16x8 vf1 = *(const f16x8*)(Vbase + voffB[ks]);
      __builtin_amdgcn_s_setprio(1);
      o0 = MFMA32(pa.v, vf0, o0);
      o1 = MFMA32(pa.v, vf1, o1);
      __builtin_amdgcn_s_setprio(0);
    }
  };

  // prologue: stage pair 0 (tiles 0,1 -> bufs 0,1)
  issue(0);
  issue(1);

  for (int T = 0; T <= Tmax; ++T) {
    BAR();  // all waves done with pair T-1 (its bufs now free)
    if (T < Tmax) {
      const int nb = 2 * ((T + 1) & 1);
      issue(nb);      // tile 2T+2
      issue(nb + 1);  // tile 2T+3
      WAITV(4);       // pair T landed; pair T+1 in flight
    } else {
      WAITV(0);
    }
    const int cb = 2 * (T & 1);
    const char* bA = lds + cb * 16384;
    const char* bB = lds + (cb + 1) * 16384;
    const int jA = 2 * T, jB = 2 * T + 1;
    if (jB <= jmax_w) {  // both tiles live: pipelined QK(A),QK(B),fin,fin
      f32x16 scA = qk(bA);
      f32x16 scB = qk(bB);
      fin(jA, bA, scA);
      fin(jB, bB, scB);
    } else if (jA <= jmax_w) {  // edge: only tile A live
      f32x16 scA = qk(bA);
      fin(jA, bA, scA);
    }
  }
  __syncthreads();  // all compute done before LDS reuse

  // epilogue: merge wkv halves through LDS, normalize, store
  float* obuf = (float*)lds;             // 4 x 8KB (per wq)
  float* lsbuf = (float*)(lds + 32768);  // 4 wq x 2 wkv x 32 q f32
  if (hi == 0) lsbuf[wq * 64 + wkv * 32 + l31] = Ls;
  if (wkv == 1) {
    float* base = obuf + wq * 2048;
#pragma unroll
    for (int dblk = 0; dblk < 2; ++dblk)
#pragma unroll
      for (int rg = 0; rg < 4; ++rg) {
        const f32x16& o = dblk ? o1 : o0;
        f32x4 t = {o[rg * 4 + 0], o[rg * 4 + 1], o[rg * 4 + 2], o[rg * 4 + 3]};
        *(f32x4*)(base + ((dblk * 4 + rg) * 64 + lane) * 4) = t;
      }
  }
  __syncthreads();
  if (wkv == 0) {
    float* base = obuf + wq * 2048;
#pragma unroll
    for (int dblk = 0; dblk < 2; ++dblk)
#pragma unroll
      for (int rg = 0; rg < 4; ++rg) {
        f32x4 t = *(f32x4*)(base + ((dblk * 4 + rg) * 64 + lane) * 4);
        f32x16& o = dblk ? o1 : o0;
#pragma unroll
        for (int i = 0; i < 4; ++i) o[rg * 4 + i] += t[i];
      }
    float inv[16];
#pragma unroll
    for (int e = 0; e < 16; ++e) {
      const int q = (e & 3) + 8 * (e >> 2) + 4 * hi;
      inv[e] = 1.0f / (lsbuf[wq * 64 + q] + lsbuf[wq * 64 + 32 + q]);
    }
    const int row0 = (qt << 7) + (wq << 5);
#pragma unroll
    for (int dblk = 0; dblk < 2; ++dblk) {
      const f32x16& o = dblk ? o1 : o0;
      const int col = h * 64 + 32 * dblk + l31;
#pragma unroll
      for (int e = 0; e < 16; ++e) {
        const int rr = row0 + (e & 3) + 8 * (e >> 2) + 4 * hi;
        vals[(size_t)rr * 1024 + col] = (f16)(o[e] * inv[e]);
      }
    }
  }
}

extern "C" void kernel_launch(void* const* d_in, const int* in_sizes, int n_in,
                              void* d_out, int out_size, void* d_ws, size_t ws_size,
                              hipStream_t stream) {
  const float* x = (const float*)d_in[0];
  const float* wq = (const float*)d_in[1];
  const float* bq = (const float*)d_in[2];
  const float* wk = (const float*)d_in[3];
  const float* bk = (const float*)d_in[4];
  const float* wv = (const float*)d_in[5];
  const float* bv = (const float*)d_in[6];
  const float* wo = (const float*)d_in[7];
  const float* bo = (const float*)d_in[8];
  const int* caus = (const int*)d_in[9];
  float* out = (float*)d_out;

  // workspace layout (fp16): 48 MiB total
  f16* xb = (f16*)d_ws;                    // [4096][1024]
  f16* wqkvT = xb + (size_t)4096 * 1024;   // [3072][1024] (n, d)
  f16* woT = wqkvT + (size_t)3072 * 1024;  // [1024][1024] (d, hk)
  f16* Qb = woT + (size_t)1024 * 1024;     // [4096][1024], log2-domain scaled
  f16* Kbuf = Qb + (size_t)4096 * 1024;    // [4096][1024]
  f16* Vt = Kbuf + (size_t)4096 * 1024;    // [1024][4096] (hk, s)
  f16* vals = Vt + (size_t)4096 * 1024;    // [4096][1024]

  k_prep<<<5120, 256, 0, stream>>>(x, xb, wq, wk, wv, wo, wqkvT, woT);
  k_gemm<0, 4, 0><<<32 * 24, 256, 0, stream>>>(xb, wqkvT, 32, 1024, bq, bk, bv,
                                               Qb, Kbuf, Vt, nullptr);
  k_fattn<<<512, 512, 0, stream>>>(Qb, Kbuf, Vt, vals, caus);
  k_gemm<1, 2, 1><<<32 * 16, 256, 0, stream>>>(vals, woT, 32, 1024, bo, nullptr,
                                               nullptr, nullptr, nullptr,
                                               nullptr, out);
}

// Round 10
// 117.125 us; speedup vs baseline: 1.3911x; 1.0031x over previous
//
#include <hip/hip_runtime.h>

typedef _Float16 f16;
typedef f16 f16x8 __attribute__((ext_vector_type(8)));
typedef f16 f16x4 __attribute__((ext_vector_type(4)));
typedef float f32x2 __attribute__((ext_vector_type(2)));
typedef float f32x4 __attribute__((ext_vector_type(4)));
typedef float f32x16 __attribute__((ext_vector_type(16)));
typedef unsigned u32;

#define MFMA16(a, b, c) __builtin_amdgcn_mfma_f32_16x16x32_f16((a), (b), (c), 0, 0, 0)
#define MFMA32(a, b, c) __builtin_amdgcn_mfma_f32_32x32x16_f16((a), (b), (c), 0, 0, 0)

#define QSCL 0.18033688011f /* 0.125 * log2(e): scores computed in log2 domain */

#define WAITV(N) asm volatile("s_waitcnt vmcnt(" #N ")" ::: "memory")
#define BAR()                          \
  {                                    \
    __builtin_amdgcn_s_barrier();      \
    __builtin_amdgcn_sched_barrier(0); \
  }

// async global->LDS, 16B per lane; dst wave-uniform base (HW adds lane*16)
__device__ __forceinline__ void gll16(const void* g, void* l) {
  __builtin_amdgcn_global_load_lds(
      (__attribute__((address_space(1))) unsigned int*)(void*)(g),
      (__attribute__((address_space(3))) unsigned int*)(l), 16, 0, 0);
}

// raw v_exp_f32 (input already in log2 domain)
__device__ __forceinline__ float ex2(float x) {
  float r;
  asm("v_exp_f32 %0, %1" : "=v"(r) : "v"(x));
  return r;
}

// v_permlane32_swap_b32: a' = [lo: a_lo | hi: b_lo], b' = [lo: a_hi | hi: b_hi]
__device__ __forceinline__ void plswap(u32& a, u32& b) {
  asm("s_nop 1\n\tv_permlane32_swap_b32 %0, %1\n\ts_nop 1" : "+v"(a), "+v"(b));
}

// two independent permlane32_swaps sharing one hazard window (saves 2 s_nop)
__device__ __forceinline__ void plswap2(u32& a, u32& b, u32& c, u32& d) {
  asm("s_nop 1\n\tv_permlane32_swap_b32 %0, %1\n\tv_permlane32_swap_b32 %2, %3\n\ts_nop 1"
      : "+v"(a), "+v"(b), "+v"(c), "+v"(d));
}

__device__ __forceinline__ u32 pk16(float lo, float hi) {
  __fp16 h2[2];
  *(decltype(__builtin_amdgcn_cvt_pkrtz(0.f, 0.f))*)h2 =
      __builtin_amdgcn_cvt_pkrtz(lo, hi);
  return *(u32*)h2;
}

// ---------------- fused prep: x->f16 + 4 weight transposes ----------------
__global__ void k_prep(const float* __restrict__ x, f16* __restrict__ xb,
                       const float* __restrict__ wq, const float* __restrict__ wk,
                       const float* __restrict__ wv, const float* __restrict__ wo,
                       f16* __restrict__ wqkvT, f16* __restrict__ woT) {
  __shared__ float tile[64][65];
  const int bid = blockIdx.x;
  if (bid < 4096) {  // x conversion, 4 floats/thread
    const int i = bid * 256 + threadIdx.x;
    float4 v = reinterpret_cast<const float4*>(x)[i];
    f16x4 o = {(f16)v.x, (f16)v.y, (f16)v.z, (f16)v.w};
    reinterpret_cast<f16x4*>(xb)[i] = o;
    return;
  }
  const int tb = bid - 4096;   // 0..1023
  const int which = tb >> 8;   // 0..3 : wq, wk, wv, wo
  const int bidx = tb & 255;
  const float* src = which == 0 ? wq : which == 1 ? wk : which == 2 ? wv : wo;
  f16* dst = which == 0 ? wqkvT
             : which == 1 ? wqkvT + (size_t)1024 * 1024
             : which == 2 ? wqkvT + (size_t)2048 * 1024
                          : woT;
  const int bc = bidx & 15, br = bidx >> 4;
  const int r0 = br << 6, c0 = bc << 6;
  const int tr = threadIdx.x >> 6, tc = threadIdx.x & 63;
#pragma unroll
  for (int p = 0; p < 16; ++p)
    tile[p * 4 + tr][tc] = src[(size_t)(r0 + p * 4 + tr) * 1024 + c0 + tc];
  __syncthreads();
#pragma unroll
  for (int p = 0; p < 16; ++p)
    dst[(size_t)(c0 + p * 4 + tr) * 1024 + r0 + tc] = (f16)tile[tc][p * 4 + tr];
}

// ---------------- GEMM: C[M][N] = A[M][Kd] * Bt[N][Kd]^T ----------------
// 128 x (NFR*32) tile, 4 waves (2x2), wave does 64 x (NFR*16).
// LDS chunk-swizzle: LDS(row, chunk) holds global(row, chunk ^ ((row>>1)&3))
// via pre-swizzled gll16 SOURCE (dest linear); reads XOR the same term.
// PAIR=0: triple-buffered BK=32 steps, counted vmcnt (proven).
// PAIR=1: 4 buffers, 2 K-steps per barrier interval.
// MODE 0 (NFR=4): QKV epilogue (bias, Q*QSCL, V transposed).
// MODE 1 (NFR=2): out-proj fp32 (128x64 tile -> 512 blocks).
template <int MODE, int NFR, int PAIR>
__global__ __launch_bounds__(256, 3) void k_gemm(
    const f16* __restrict__ A, const f16* __restrict__ Bt, int nbm, int Kd,
    const float* __restrict__ bias0, const float* __restrict__ bias1,
    const float* __restrict__ bias2,
    f16* __restrict__ Qo, f16* __restrict__ Ko, f16* __restrict__ Vo,
    float* __restrict__ Fo) {
  constexpr int TSZ = 8192 + NFR * 2048;  // per-buffer: A 8KB | B NFR*2KB
  constexpr int NBUF = PAIR ? 4 : 3;
  __shared__ __align__(16) char smem[NBUF * TSZ];
  const int tid = threadIdx.x;
  const int wid = tid >> 6, lane = tid & 63;
  const int r = lane & 15, t = lane >> 4;
  const int bm = blockIdx.x % nbm, bn = blockIdx.x / nbm;
  const int m0 = bm << 7, n0 = bn * (NFR * 32);
  const int wr = wid >> 1, wc = wid & 1;

  const f32x4 vz = {0.f, 0.f, 0.f, 0.f};
  f32x4 acc[4][NFR];
#pragma unroll
  for (int m = 0; m < 4; ++m)
#pragma unroll
    for (int n = 0; n < NFR; ++n) acc[m][n] = vz;

  const int srow = tid >> 2;  // staged row 0..63 (+64 on second issue)
  // chunk pre-swizzle: LDS chunk (tid&3) receives global chunk ^(srow>>1 &3)
  const int scb = (((tid & 3) ^ ((tid >> 3) & 3)) << 4);
  const size_t ldb = (size_t)Kd * 2;
  const char* Ab = (const char*)A + (size_t)m0 * ldb + scb;
  const char* Bb = (const char*)Bt + (size_t)n0 * ldb + scb;

  auto issue = [&](int kt, int buf) {
    const size_t kb = (size_t)kt << 6;
    char* base = smem + buf * TSZ;
    gll16(Ab + (size_t)srow * ldb + kb, base + wid * 1024);
    gll16(Ab + (size_t)(srow + 64) * ldb + kb, base + 4096 + wid * 1024);
    gll16(Bb + (size_t)srow * ldb + kb, base + 8192 + wid * 1024);
    if (NFR == 4)
      gll16(Bb + (size_t)(srow + 64) * ldb + kb, base + 8192 + 4096 + wid * 1024);
  };

  const int swz = ((r >> 1) & 3) << 4;  // read-side chunk swizzle (bytes)

  auto comp = [&](int buf) {
    const char* base = smem + buf * TSZ;
    f16x8 af[4], bg[NFR];
#pragma unroll
    for (int m = 0; m < 4; ++m)
      af[m] = *(const f16x8*)(base + ((wr * 64 + m * 16 + r) * 64 +
                                      ((t * 16) ^ swz)));
#pragma unroll
    for (int n = 0; n < NFR; ++n)
      bg[n] = *(const f16x8*)(base + 8192 +
                              ((wc * (NFR * 16) + n * 16 + r) * 64 +
                               ((t * 16) ^ swz)));
    __builtin_amdgcn_s_setprio(1);
#pragma unroll
    for (int m = 0; m < 4; ++m)
#pragma unroll
      for (int n = 0; n < NFR; ++n) acc[m][n] = MFMA16(af[m], bg[n], acc[m][n]);
    __builtin_amdgcn_s_setprio(0);
  };

  const int nk = Kd >> 5;  // 32
  if (PAIR) {
    // pair-wise: 4 bufs, step s -> buf s&3; one barrier per 2 K-steps
    issue(0, 0);
    issue(1, 1);
    const int nsup = nk >> 1;
    for (int T = 0; T < nsup; ++T) {
      WAITV(0);  // own pair T landed (issued a full super-step ago)
      BAR();     // all waves' pair T visible; pair T-1 bufs free
      if (T + 1 < nsup) {
        issue(2 * T + 2, (2 * T + 2) & 3);
        issue(2 * T + 3, (2 * T + 3) & 3);
      }
      comp((2 * T) & 3);
      comp((2 * T + 1) & 3);
    }
  } else {
    issue(0, 0);
    issue(1, 1);
    int b = 0, bi = 2;
    for (int kt = 0; kt < nk; ++kt) {
      if (kt + 1 < nk) {
        if (NFR == 4) {
          WAITV(4);
        } else {
          WAITV(3);
        }
      } else {
        WAITV(0);
      }
      BAR();
      if (kt + 2 < nk) issue(kt + 2, bi);
      comp(b);
      b = (b == 2) ? 0 : b + 1;
      bi = (bi == 2) ? 0 : bi + 1;
    }
  }

#pragma unroll
  for (int m = 0; m < 4; ++m) {
    const int row0 = m0 + wr * 64 + m * 16 + t * 4;
#pragma unroll
    for (int n = 0; n < NFR; ++n) {
      const int gc = n0 + wc * (NFR * 16) + n * 16 + r;
      if (MODE == 0) {
        const float b2 = gc < 1024 ? bias0[gc]
                                   : (gc < 2048 ? bias1[gc - 1024] : bias2[gc - 2048]);
        float v[4];
#pragma unroll
        for (int i = 0; i < 4; ++i) v[i] = acc[m][n][i] + b2;
        if (gc < 1024) {  // Q, pre-scaled into log2 domain
#pragma unroll
          for (int i = 0; i < 4; ++i)
            Qo[(size_t)(row0 + i) * 1024 + gc] = (f16)(v[i] * QSCL);
        } else if (gc < 2048) {  // K natural layout
#pragma unroll
          for (int i = 0; i < 4; ++i)
            Ko[(size_t)(row0 + i) * 1024 + (gc - 1024)] = (f16)v[i];
        } else {  // V transposed: Vt[hk][s]
          f16x4 pk = {(f16)v[0], (f16)v[1], (f16)v[2], (f16)v[3]};
          *(f16x4*)(Vo + (size_t)(gc - 2048) * 4096 + row0) = pk;
        }
      } else {
        const float b2 = bias0[gc];
#pragma unroll
        for (int i = 0; i < 4; ++i)
          Fo[(size_t)(row0 + i) * 1024 + gc] = acc[m][n][i] + b2;
      }
    }
  }
}

// ---------------- flash attention (32x32 MFMA, merged pair block) --------
// ROUND-10: the two co-resident blocks of round 3 (same head h, qt pair
// {31-pi, pi}, both streaming K/V from tile 0) are MERGED into one
// 1024-thread block (16 waves = two 8-wave compute teams, h2 = W>>3
// selects the qt). ONE shared K/V staging stream: waves 0-7 stage K rows
// [8W,8W+8), waves 8-15 stage V rows — exactly 1 gll16 per wave per tile
// (WAITV(2) per pair). This HALVES LDS staging writes and L2 request
// traffic vs two duplicate streams, with identical aligned-prefix
// locality (the property round 8 proved is worth 2x). Per-tile compute
// bodies (qk/fin), masks, 4-buf pair scheme, and epilogue are verbatim
// round 9 with qt -> qt_w and per-half scratch. Small-qt waves finish
// computing early (jmax_w guard) but keep staging+BAR to the block's
// Tmax — same idle as the old separate small block, minus its staging.
__global__ __launch_bounds__(1024, 4) void k_fattn(
    const f16* __restrict__ Q, const f16* __restrict__ Kb,
    const f16* __restrict__ Vt, f16* __restrict__ vals,
    const int* __restrict__ causp) {
  __shared__ uint4 ldsv[4224];  // 67584 B: 4x16KB KV bufs | 64KB+2KB epilogue
  char* lds = (char*)ldsv;
  const int tid = threadIdx.x;
  const int W = tid >> 6, lane = tid & 63;
  const int l31 = lane & 31, hi = lane >> 5;
  const int h2 = W >> 3;           // which qt of the pair
  const int Wl = W & 7;            // wave within the 8-wave team
  const int wq = Wl >> 1, wkv = Wl & 1;
  const int h = blockIdx.x & 15;
  const int pi = blockIdx.x >> 4;  // 0..15
  const int qt = h2 == 0 ? 31 - pi : pi;  // team's q-tile
  const int cz = *causp;
  const int Tmax = cz ? (31 - pi) : 31;  // block loop bound = big team's
  const int dw = wq - wkv;               // -1..3
  const int jmax_w = cz ? (2 * qt + (dw >= 2 ? 1 : 0) - (dw < 0 ? 1 : 0)) : 63;
  const bool maskd = cz && ((dw & 1) == 0);  // dw == 0 or 2: diagonal tile

  // Q B-frags: col q = 128qt + 32wq + l31, k = d = 16s + 8hi + 0..7
  const size_t qrow = (size_t)((qt << 7) + (wq << 5) + l31) * 1024 + h * 64;
  f16x8 qf[4];
#pragma unroll
  for (int s = 0; s < 4; ++s) qf[s] = *(const f16x8*)(Q + qrow + 16 * s + 8 * hi);

  f32x16 o0, o1, zv;
#pragma unroll
  for (int e = 0; e < 16; ++e) { o0[e] = 0.f; o1[e] = 0.f; zv[e] = 0.f; }
  float Ls = 0.f;  // running row-sum for q = 32*wq + l31 (this wkv half)

  // staging (shared stream, 1 gll16/wave/tile): waves 0-7 -> K rows
  // [8W,8W+8); waves 8-15 -> V rows [8(W-8),8(W-8)+8). Source pre-swizzled
  // chunk sch reads global chunk sch ^ (row&7); dest linear.
  const int srw = lane >> 3, sch = lane & 7;
  const int ssw = (sch ^ srw) << 3;  // f16-element offset within row
  const char* gcur;
  size_t gstep;
  int sdst;
  if (W < 8) {
    gcur = (const char*)(Kb + (size_t)(8 * W + srw) * 1024 + h * 64 + ssw);
    gstep = (size_t)64 * 2048;  // next kv tile: 64 K rows
    sdst = W * 1024;
  } else {
    gcur = (const char*)(Vt + (size_t)(h * 64 + 8 * (W - 8) + srw) * 4096 + ssw);
    gstep = 128;  // next kv tile: 64 s cols * 2B
    sdst = 8192 + (W - 8) * 1024;
  }

  auto issue = [&](int buf) {
    gll16(gcur, lds + buf * 16384 + sdst);
    gcur += gstep;
  };

  // LDS read offsets (loop-invariant, hoisted)
  const int krow = (wkv << 5) + l31, ksw = krow & 7;
  const int vsw = l31 & 7;  // V rows l31 and 32+l31 share row&7
  int koff[4];
#pragma unroll
  for (int s = 0; s < 4; ++s)
    koff[s] = krow * 128 + (((2 * s + hi) ^ ksw) << 4);
  int voffA[2], voffB[2];
#pragma unroll
  for (int ks = 0; ks < 2; ++ks) {
    const int cl = 4 * wkv + 2 * ks + hi;
    voffA[ks] = l31 * 128 + ((cl ^ vsw) << 4);
    voffB[ks] = (32 + l31) * 128 + ((cl ^ vsw) << 4);
  }

  // QK^T chain for one tile (af frags loaded inside: short live range)
  auto qk = [&](const char* Kbase) -> f32x16 {
    f16x8 af[4];
#pragma unroll
    for (int s = 0; s < 4; ++s)
      af[s] = *(const f16x8*)(Kbase + koff[s]);
    __builtin_amdgcn_s_setprio(1);
    f32x16 sc = MFMA32(af[0], qf[0], zv);
#pragma unroll
    for (int s = 1; s < 4; ++s) sc = MFMA32(af[s], qf[s], sc);
    __builtin_amdgcn_s_setprio(0);
    return sc;
  };

  // finish one tile: mask -> exp -> rowsum (packed) -> pack/swap -> PV
  auto fin = [&](int j, const char* Kbase, f32x16& sc) {
    const char* Vbase = Kbase + 8192;
    if (maskd && j == jmax_w) {  // diagonal: mask kv_local > q_local
#pragma unroll
      for (int e = 0; e < 16; ++e) {
        const int kvr = (e & 3) + 8 * (e >> 2) + 4 * hi;
        if (kvr > l31) sc[e] = -1e9f;
      }
    }
    f32x2 p2[8];
#pragma unroll
    for (int e = 0; e < 8; ++e) {
      f32x2 t;
      t[0] = ex2(sc[2 * e]);
      t[1] = ex2(sc[2 * e + 1]);
      p2[e] = t;
    }
    // packed-pair row-sum: 7 v_pk_add_f32 + 1 scalar; cross-half via plswap
    {
      f32x2 a0 = p2[0] + p2[1];
      f32x2 a1 = p2[2] + p2[3];
      f32x2 a2 = p2[4] + p2[5];
      f32x2 a3 = p2[6] + p2[7];
      f32x2 b0 = a0 + a1;
      f32x2 b1 = a2 + a3;
      f32x2 c = b0 + b1;
      float s = c[0] + c[1];
      union { float f; u32 u; } ua, ub;
      ua.f = s; ub.f = s;
      plswap(ua.u, ub.u);
      Ls += ua.f + ub.f;
    }
    // two 16-kv windows -> PV A-frags via pack + fused double-permlane
#pragma unroll
    for (int ks = 0; ks < 2; ++ks) {
      u32 c0 = pk16(p2[4 * ks + 0][0], p2[4 * ks + 0][1]);
      u32 c1 = pk16(p2[4 * ks + 1][0], p2[4 * ks + 1][1]);
      u32 c2 = pk16(p2[4 * ks + 2][0], p2[4 * ks + 2][1]);
      u32 c3 = pk16(p2[4 * ks + 3][0], p2[4 * ks + 3][1]);
      plswap2(c0, c2, c1, c3);
      union { u32 w[4]; f16x8 v; } pa;
      pa.w[0] = c0; pa.w[1] = c1; pa.w[2] = c2; pa.w[3] = c3;
      const f16x8 vf0 = *(const f16x8*)(Vbase + voffA[ks]);
      const f16x8 vf1 = *(const f16x8*)(Vbase + voffB[ks]);
      __builtin_amdgcn_s_setprio(1);
      o0 = MFMA32(pa.v, vf0, o0);
      o1 = MFMA32(pa.v, vf1, o1);
      __builtin_amdgcn_s_setprio(0);
    }
  };

  // prologue: stage pair 0 (tiles 0,1 -> bufs 0,1)
  issue(0);
  issue(1);

  for (int T = 0; T <= Tmax; ++T) {
    BAR();  // all waves done with pair T-1 (its bufs now free)
    if (T < Tmax) {
      const int nb = 2 * ((T + 1) & 1);
      issue(nb);      // tile 2T+2
      issue(nb + 1);  // tile 2T+3
      WAITV(2);       // own pair-T load landed; pair T+1 in flight
    } else {
      WAITV(0);
    }
    const int cb = 2 * (T & 1);
    const char* bA = lds + cb * 16384;
    const char* bB = lds + (cb + 1) * 16384;
    const int jA = 2 * T, jB = 2 * T + 1;
    if (jB <= jmax_w) {  // both tiles live: pipelined QK(A),QK(B),fin,fin
      f32x16 scA = qk(bA);
      f32x16 scB = qk(bB);
      fin(jA, bA, scA);
      fin(jB, bB, scB);
    } else if (jA <= jmax_w) {  // edge: only tile A live
      f32x16 scA = qk(bA);
      fin(jA, bA, scA);
    }
  }
  __syncthreads();  // all compute done before LDS reuse

  // epilogue: per-half scratch (disjoint); merge wkv halves, normalize,
  // store. obuf: 2 halves x 4 wq x 8KB; lsbuf: 2 halves x 256 f32.
  float* obuf = (float*)(lds + h2 * 32768);
  float* lsbuf = (float*)(lds + 65536 + h2 * 1024);
  if (hi == 0) lsbuf[wq * 64 + wkv * 32 + l31] = Ls;
  if (wkv == 1) {
    float* base = obuf + wq * 2048;
#pragma unroll
    for (int dblk = 0; dblk < 2; ++dblk)
#pragma unroll
      for (int rg = 0; rg < 4; ++rg) {
        const f32x16& o = dblk ? o1 : o0;
        f32x4 t = {o[rg * 4 + 0], o[rg * 4 + 1], o[rg * 4 + 2], o[rg * 4 + 3]};
        *(f32x4*)(base + ((dblk * 4 + rg) * 64 + lane) * 4) = t;
      }
  }
  __syncthreads();
  if (wkv == 0) {
    float* base = obuf + wq * 2048;
#pragma unroll
    for (int dblk = 0; dblk < 2; ++dblk)
#pragma unroll
      for (int rg = 0; rg < 4; ++rg) {
        f32x4 t = *(f32x4*)(base + ((dblk * 4 + rg) * 64 + lane) * 4);
        f32x16& o = dblk ? o1 : o0;
#pragma unroll
        for (int i = 0; i < 4; ++i) o[rg * 4 + i] += t[i];
      }
    float inv[16];
#pragma unroll
    for (int e = 0; e < 16; ++e) {
      const int q = (e & 3) + 8 * (e >> 2) + 4 * hi;
      inv[e] = 1.0f / (lsbuf[wq * 64 + q] + lsbuf[wq * 64 + 32 + q]);
    }
    const int row0 = (qt << 7) + (wq << 5);
#pragma unroll
    for (int dblk = 0; dblk < 2; ++dblk) {
      const f32x16& o = dblk ? o1 : o0;
      const int col = h * 64 + 32 * dblk + l31;
#pragma unroll
      for (int e = 0; e < 16; ++e) {
        const int rr = row0 + (e & 3) + 8 * (e >> 2) + 4 * hi;
        vals[(size_t)rr * 1024 + col] = (f16)(o[e] * inv[e]);
      }
    }
  }
}

extern "C" void kernel_launch(void* const* d_in, const int* in_sizes, int n_in,
                              void* d_out, int out_size, void* d_ws, size_t ws_size,
                              hipStream_t stream) {
  const float* x = (const float*)d_in[0];
  const float* wq = (const float*)d_in[1];
  const float* bq = (const float*)d_in[2];
  const float* wk = (const float*)d_in[3];
  const float* bk = (const float*)d_in[4];
  const float* wv = (const float*)d_in[5];
  const float* bv = (const float*)d_in[6];
  const float* wo = (const float*)d_in[7];
  const float* bo = (const float*)d_in[8];
  const int* caus = (const int*)d_in[9];
  float* out = (float*)d_out;

  // workspace layout (fp16): 48 MiB total
  f16* xb = (f16*)d_ws;                    // [4096][1024]
  f16* wqkvT = xb + (size_t)4096 * 1024;   // [3072][1024] (n, d)
  f16* woT = wqkvT + (size_t)3072 * 1024;  // [1024][1024] (d, hk)
  f16* Qb = woT + (size_t)1024 * 1024;     // [4096][1024], log2-domain scaled
  f16* Kbuf = Qb + (size_t)4096 * 1024;    // [4096][1024]
  f16* Vt = Kbuf + (size_t)4096 * 1024;    // [1024][4096] (hk, s)
  f16* vals = Vt + (size_t)4096 * 1024;    // [4096][1024]

  k_prep<<<5120, 256, 0, stream>>>(x, xb, wq, wk, wv, wo, wqkvT, woT);
  k_gemm<0, 4, 0><<<32 * 24, 256, 0, stream>>>(xb, wqkvT, 32, 1024, bq, bk, bv,
                                               Qb, Kbuf, Vt, nullptr);
  k_fattn<<<256, 1024, 0, stream>>>(Qb, Kbuf, Vt, vals, caus);
  k_gemm<1, 2, 1><<<32 * 16, 256, 0, stream>>>(vals, woT, 32, 1024, bo, nullptr,
                                               nullptr, nullptr, nullptr,
                                               nullptr, out);
}